// Round 1
// baseline (3908.828 us; speedup 1.0000x reference)
//
#include <hip/hip_runtime.h>
#include <hip/hip_bf16.h>
#include <cstddef>

// ---------------------------------------------------------------------------
// Problem constants
// ---------------------------------------------------------------------------
#define B_ 16
#define H_ 256
#define W_ 256
#define HW_ (H_ * W_)

// ---------------------------------------------------------------------------
// Feature extraction kernel: x [B,3,H,W] -> F [B,32,H,W]
//   ch0      : prnu  = gray - gauss5x5(gray)
//   ch1..30  : SRM filter bank on gray (cross-correlation, zero pad)
//   ch31     : cfa   = green - avg4(green)
// ---------------------------------------------------------------------------
__global__ __launch_bounds__(256) void feat_kernel(const float* __restrict__ x,
                                                   float* __restrict__ F) {
  __shared__ float sg[36][37];   // gray  tile with halo 2, +1 pad
  __shared__ float sgr[36][37];  // green tile with halo 2, +1 pad

  const int b = blockIdx.z;
  const int y0 = blockIdx.y * 32;
  const int x0 = blockIdx.x * 32;
  const float* xb = x + (size_t)b * 3 * HW_;

  for (int i = threadIdx.x; i < 36 * 36; i += 256) {
    int iy = i / 36, ix = i % 36;
    int gy = y0 + iy - 2, gx = x0 + ix - 2;
    float gray = 0.f, green = 0.f;
    if (gy >= 0 && gy < H_ && gx >= 0 && gx < W_) {
      int idx = gy * W_ + gx;
      float r = fminf(fmaxf(xb[idx] * 0.229f + 0.485f, 0.f), 1.f);
      float g = fminf(fmaxf(xb[idx + HW_] * 0.224f + 0.456f, 0.f), 1.f);
      float bl = fminf(fmaxf(xb[idx + 2 * HW_] * 0.225f + 0.406f, 0.f), 1.f);
      gray = 0.299f * r + 0.587f * g + 0.114f * bl;
      green = g;
    }
    sg[iy][ix] = gray;
    sgr[iy][ix] = green;
  }
  __syncthreads();

  for (int p = threadIdx.x; p < 32 * 32; p += 256) {
    const int py = p >> 5, px = p & 31;
    const int ly = py + 2, lx = px + 2;
#define G(dy, dx) sg[ly + (dy)][lx + (dx)]
    float f[32];
    const float c = G(0, 0);

    // --- prnu: gray - gauss ---
    {
      const float ga[5] = {1.f, 4.f, 6.f, 4.f, 1.f};
      float s = 0.f;
#pragma unroll
      for (int i = 0; i < 5; i++) {
        float rs = 0.f;
#pragma unroll
        for (int j = 0; j < 5; j++) rs += ga[j] * G(i - 2, j - 2);
        s += ga[i] * rs;
      }
      f[0] = c - s * (1.0f / 256.0f);
    }

    const int dy8[8] = {-1, -1, 0, 1, 1, 1, 0, -1};
    const int dx8[8] = {0, 1, 1, 1, 0, -1, -1, -1};

    // --- 1st order (8) ---
#pragma unroll
    for (int k = 0; k < 8; k++) f[1 + k] = G(dy8[k], dx8[k]) - c;

    // --- 2nd order (4) ---
#pragma unroll
    for (int k = 0; k < 4; k++)
      f[9 + k] = 0.5f * (G(dy8[k], dx8[k]) + G(-dy8[k], -dx8[k])) - c;

    // --- 3rd order (8) ---
#pragma unroll
    for (int k = 0; k < 8; k++)
      f[13 + k] = (-G(-dy8[k], -dx8[k]) + 3.f * c - 3.f * G(dy8[k], dx8[k]) +
                   G(2 * dy8[k], 2 * dx8[k])) * (1.f / 3.f);

    // --- SQ3 ---
    {
      const float sq3[3][3] = {{-1, 2, -1}, {2, -4, 2}, {-1, 2, -1}};
      float s = 0.f;
#pragma unroll
      for (int i = 0; i < 3; i++)
#pragma unroll
        for (int j = 0; j < 3; j++) s += sq3[i][j] * G(i - 1, j - 1);
      f[21] = s * 0.25f;
    }
    // --- SQ5 ---
    {
      const float sq5[5][5] = {{-1, 2, -2, 2, -1},
                               {2, -6, 8, -6, 2},
                               {-2, 8, -12, 8, -2},
                               {2, -6, 8, -6, 2},
                               {-1, 2, -2, 2, -1}};
      float s = 0.f;
#pragma unroll
      for (int i = 0; i < 5; i++)
#pragma unroll
        for (int j = 0; j < 5; j++) s += sq5[i][j] * G(i - 2, j - 2);
      f[22] = s * (1.0f / 12.0f);
    }
    // --- e3 rotations (4): rot90 CCW index maps ---
    {
      const float e3[3][3] = {{-1, 2, -1}, {2, -4, 2}, {0, 0, 0}};
      float s0 = 0.f, s1 = 0.f, s2 = 0.f, s3 = 0.f;
#pragma unroll
      for (int i = 0; i < 3; i++)
#pragma unroll
        for (int j = 0; j < 3; j++) {
          float v = G(i - 1, j - 1);
          s0 += e3[i][j] * v;          // r=0
          s1 += e3[j][2 - i] * v;      // r=1
          s2 += e3[2 - i][2 - j] * v;  // r=2
          s3 += e3[2 - j][i] * v;      // r=3
        }
      f[23] = s0 * 0.25f;
      f[24] = s1 * 0.25f;
      f[25] = s2 * 0.25f;
      f[26] = s3 * 0.25f;
    }
    // --- e5 rotations (4) ---
    {
      const float e5[5][5] = {{-1, 2, -2, 2, -1},
                              {2, -6, 8, -6, 2},
                              {-2, 8, -12, 8, -2},
                              {0, 0, 0, 0, 0},
                              {0, 0, 0, 0, 0}};
      float s0 = 0.f, s1 = 0.f, s2 = 0.f, s3 = 0.f;
#pragma unroll
      for (int i = 0; i < 5; i++)
#pragma unroll
        for (int j = 0; j < 5; j++) {
          float v = G(i - 2, j - 2);
          s0 += e5[i][j] * v;
          s1 += e5[j][4 - i] * v;
          s2 += e5[4 - i][4 - j] * v;
          s3 += e5[4 - j][i] * v;
        }
      f[27] = s0 * 0.25f;
      f[28] = s1 * 0.25f;
      f[29] = s2 * 0.25f;
      f[30] = s3 * 0.25f;
    }
    // --- cfa ---
    {
      float gc = sgr[ly][lx];
      f[31] = gc - 0.25f * (sgr[ly - 1][lx] + sgr[ly][lx - 1] +
                            sgr[ly][lx + 1] + sgr[ly + 1][lx]);
    }
#undef G

    size_t base = ((size_t)b * 32) * HW_ + (size_t)(y0 + py) * W_ + (x0 + px);
#pragma unroll
    for (int cc = 0; cc < 32; cc++) F[base + (size_t)cc * HW_] = f[cc];
  }
}

// ---------------------------------------------------------------------------
// Direct conv3x3 (SAME, zero pad) + fused BN + ReLU.
// Block: 32(W) x 8(H) pixel tile, all 64 output channels. 256 threads.
// Thread: 8 couts x (2y x 4x) pixels = 64 fp32 accumulators.
// Input staged in LDS 8 cin at a time; weights staged as [ci][tap][co].
// ---------------------------------------------------------------------------
template <int CIN>
__global__ __launch_bounds__(256) void conv_bn_relu(
    const float* __restrict__ in, const float* __restrict__ w,
    const float* __restrict__ bias, const float* __restrict__ gam,
    const float* __restrict__ bet, const float* __restrict__ mean,
    const float* __restrict__ var, float* __restrict__ out) {
  constexpr int WT = 32, HT = 8, CK = 8;
  __shared__ float s_in[CK][HT + 2][WT + 3];  // [8][10][35] (+1 pad col)
  __shared__ float s_w[CK][9][64];

  const int tid = threadIdx.x;
  const int b = blockIdx.z;
  const int y0 = blockIdx.y * HT;
  const int x0 = blockIdx.x * WT;

  const int co_grp = tid >> 5;        // 0..7
  const int pg = tid & 31;            // 0..31
  const int px0 = (pg & 7) * 4;       // 0,4,..,28
  const int py0 = (pg >> 3) * 2;      // 0,2,4,6
  const int co0 = co_grp * 8;

  float acc[2][4][8];
#pragma unroll
  for (int yy = 0; yy < 2; yy++)
#pragma unroll
    for (int xx = 0; xx < 4; xx++)
#pragma unroll
      for (int j = 0; j < 8; j++) acc[yy][xx][j] = 0.f;

  for (int c0 = 0; c0 < CIN; c0 += CK) {
    __syncthreads();
    // stage input chunk [8 cin][10 rows][34 cols], zero-padded at borders
    for (int i = tid; i < CK * (HT + 2) * (WT + 2); i += 256) {
      int ci = i / ((HT + 2) * (WT + 2));
      int rem = i % ((HT + 2) * (WT + 2));
      int yy = rem / (WT + 2);
      int xx = rem % (WT + 2);
      int gy = y0 + yy - 1, gx = x0 + xx - 1;
      float v = 0.f;
      if (gy >= 0 && gy < H_ && gx >= 0 && gx < W_)
        v = in[(((size_t)b * CIN + (c0 + ci)) * H_ + gy) * W_ + gx];
      s_in[ci][yy][xx] = v;
    }
    // stage weight chunk: s_w[ci][tap][co]
    for (int i = tid; i < CK * 9 * 64; i += 256) {
      int co = i & 63;
      int tap = (i >> 6) % 9;
      int ci = i / (9 * 64);
      s_w[ci][tap][co] = w[((size_t)co * CIN + (c0 + ci)) * 9 + tap];
    }
    __syncthreads();

#pragma unroll
    for (int ci = 0; ci < CK; ci++) {
#pragma unroll
      for (int ky = 0; ky < 3; ky++) {
#pragma unroll
        for (int kx = 0; kx < 3; kx++) {
          float wv[8];
#pragma unroll
          for (int j = 0; j < 8; j++) wv[j] = s_w[ci][ky * 3 + kx][co0 + j];
          float iv[2][4];
#pragma unroll
          for (int yy = 0; yy < 2; yy++)
#pragma unroll
            for (int xx = 0; xx < 4; xx++)
              iv[yy][xx] = s_in[ci][py0 + yy + ky][px0 + xx + kx];
#pragma unroll
          for (int yy = 0; yy < 2; yy++)
#pragma unroll
            for (int xx = 0; xx < 4; xx++)
#pragma unroll
              for (int j = 0; j < 8; j++)
                acc[yy][xx][j] += iv[yy][xx] * wv[j];
        }
      }
    }
  }

  // epilogue: fold conv bias + BN, ReLU, store
#pragma unroll
  for (int j = 0; j < 8; j++) {
    int co = co0 + j;
    float s = gam[co] * rsqrtf(var[co] + 1e-5f);
    float t = bet[co] + (bias[co] - mean[co]) * s;
#pragma unroll
    for (int yy = 0; yy < 2; yy++) {
#pragma unroll
      for (int xx = 0; xx < 4; xx++) {
        float v = acc[yy][xx][j] * s + t;
        v = fmaxf(v, 0.f);
        out[(((size_t)b * 64 + co) * H_ + (y0 + py0 + yy)) * W_ +
            (x0 + px0 + xx)] = v;
      }
    }
  }
}

// ---------------------------------------------------------------------------
// Launch
// ---------------------------------------------------------------------------
extern "C" void kernel_launch(void* const* d_in, const int* in_sizes, int n_in,
                              void* d_out, int out_size, void* d_ws,
                              size_t ws_size, hipStream_t stream) {
  const float* x = (const float*)d_in[0];
#define LAYER_PTRS(i)                                                       \
  const float* w##i = (const float*)d_in[1 + ((i)-1) * 6 + 0];              \
  const float* b##i = (const float*)d_in[1 + ((i)-1) * 6 + 1];              \
  const float* g##i = (const float*)d_in[1 + ((i)-1) * 6 + 2];              \
  const float* be##i = (const float*)d_in[1 + ((i)-1) * 6 + 3];             \
  const float* m##i = (const float*)d_in[1 + ((i)-1) * 6 + 4];              \
  const float* v##i = (const float*)d_in[1 + ((i)-1) * 6 + 5];
  LAYER_PTRS(1)
  LAYER_PTRS(2)
  LAYER_PTRS(3)
  LAYER_PTRS(4)
#undef LAYER_PTRS

  float* feat = (float*)d_ws;  // [16,32,256,256] fp32 = 134,217,728 B
  float* buf1 = (float*)((char*)d_ws + (size_t)134217728);  // [16,64,256,256]
  float* out = (float*)d_out;

  dim3 fgrid(W_ / 32, H_ / 32, B_);
  feat_kernel<<<fgrid, 256, 0, stream>>>(x, feat);

  dim3 cgrid(W_ / 32, H_ / 8, B_);
  conv_bn_relu<32><<<cgrid, 256, 0, stream>>>(feat, w1, b1, g1, be1, m1, v1, buf1);
  conv_bn_relu<64><<<cgrid, 256, 0, stream>>>(buf1, w2, b2, g2, be2, m2, v2, out);
  conv_bn_relu<64><<<cgrid, 256, 0, stream>>>(out, w3, b3, g3, be3, m3, v3, buf1);
  conv_bn_relu<64><<<cgrid, 256, 0, stream>>>(buf1, w4, b4, g4, be4, m4, v4, out);
}

// Round 2
// 823.037 us; speedup vs baseline: 4.7493x; 4.7493x over previous
//
#include <hip/hip_runtime.h>
#include <hip/hip_bf16.h>
#include <cstddef>

#define B_ 16
#define H_ 256
#define W_ 256
#define HW_ (H_ * W_)

typedef _Float16 half8 __attribute__((ext_vector_type(8)));
typedef float floatx4 __attribute__((ext_vector_type(4)));

// ---------------------------------------------------------------------------
// Feature extraction: x [B,3,H,W] fp32 -> F [B,H,W,32] fp16 (NHWC)
// ---------------------------------------------------------------------------
__global__ __launch_bounds__(256) void feat_kernel(const float* __restrict__ x,
                                                   _Float16* __restrict__ F) {
  __shared__ float sg[36][37];
  __shared__ float sgr[36][37];

  const int b = blockIdx.z;
  const int y0 = blockIdx.y * 32;
  const int x0 = blockIdx.x * 32;
  const float* xb = x + (size_t)b * 3 * HW_;

  for (int i = threadIdx.x; i < 36 * 36; i += 256) {
    int iy = i / 36, ix = i % 36;
    int gy = y0 + iy - 2, gx = x0 + ix - 2;
    float gray = 0.f, green = 0.f;
    if (gy >= 0 && gy < H_ && gx >= 0 && gx < W_) {
      int idx = gy * W_ + gx;
      float r = fminf(fmaxf(xb[idx] * 0.229f + 0.485f, 0.f), 1.f);
      float g = fminf(fmaxf(xb[idx + HW_] * 0.224f + 0.456f, 0.f), 1.f);
      float bl = fminf(fmaxf(xb[idx + 2 * HW_] * 0.225f + 0.406f, 0.f), 1.f);
      gray = 0.299f * r + 0.587f * g + 0.114f * bl;
      green = g;
    }
    sg[iy][ix] = gray;
    sgr[iy][ix] = green;
  }
  __syncthreads();

  for (int p = threadIdx.x; p < 32 * 32; p += 256) {
    const int py = p >> 5, px = p & 31;
    const int ly = py + 2, lx = px + 2;
#define G(dy, dx) sg[ly + (dy)][lx + (dx)]
    float f[32];
    const float c = G(0, 0);

    {
      const float ga[5] = {1.f, 4.f, 6.f, 4.f, 1.f};
      float s = 0.f;
#pragma unroll
      for (int i = 0; i < 5; i++) {
        float rs = 0.f;
#pragma unroll
        for (int j = 0; j < 5; j++) rs += ga[j] * G(i - 2, j - 2);
        s += ga[i] * rs;
      }
      f[0] = c - s * (1.0f / 256.0f);
    }

    const int dy8[8] = {-1, -1, 0, 1, 1, 1, 0, -1};
    const int dx8[8] = {0, 1, 1, 1, 0, -1, -1, -1};

#pragma unroll
    for (int k = 0; k < 8; k++) f[1 + k] = G(dy8[k], dx8[k]) - c;
#pragma unroll
    for (int k = 0; k < 4; k++)
      f[9 + k] = 0.5f * (G(dy8[k], dx8[k]) + G(-dy8[k], -dx8[k])) - c;
#pragma unroll
    for (int k = 0; k < 8; k++)
      f[13 + k] = (-G(-dy8[k], -dx8[k]) + 3.f * c - 3.f * G(dy8[k], dx8[k]) +
                   G(2 * dy8[k], 2 * dx8[k])) * (1.f / 3.f);

    {
      const float sq3[3][3] = {{-1, 2, -1}, {2, -4, 2}, {-1, 2, -1}};
      float s = 0.f;
#pragma unroll
      for (int i = 0; i < 3; i++)
#pragma unroll
        for (int j = 0; j < 3; j++) s += sq3[i][j] * G(i - 1, j - 1);
      f[21] = s * 0.25f;
    }
    {
      const float sq5[5][5] = {{-1, 2, -2, 2, -1},
                               {2, -6, 8, -6, 2},
                               {-2, 8, -12, 8, -2},
                               {2, -6, 8, -6, 2},
                               {-1, 2, -2, 2, -1}};
      float s = 0.f;
#pragma unroll
      for (int i = 0; i < 5; i++)
#pragma unroll
        for (int j = 0; j < 5; j++) s += sq5[i][j] * G(i - 2, j - 2);
      f[22] = s * (1.0f / 12.0f);
    }
    {
      const float e3[3][3] = {{-1, 2, -1}, {2, -4, 2}, {0, 0, 0}};
      float s0 = 0.f, s1 = 0.f, s2 = 0.f, s3 = 0.f;
#pragma unroll
      for (int i = 0; i < 3; i++)
#pragma unroll
        for (int j = 0; j < 3; j++) {
          float v = G(i - 1, j - 1);
          s0 += e3[i][j] * v;
          s1 += e3[j][2 - i] * v;
          s2 += e3[2 - i][2 - j] * v;
          s3 += e3[2 - j][i] * v;
        }
      f[23] = s0 * 0.25f;
      f[24] = s1 * 0.25f;
      f[25] = s2 * 0.25f;
      f[26] = s3 * 0.25f;
    }
    {
      const float e5[5][5] = {{-1, 2, -2, 2, -1},
                              {2, -6, 8, -6, 2},
                              {-2, 8, -12, 8, -2},
                              {0, 0, 0, 0, 0},
                              {0, 0, 0, 0, 0}};
      float s0 = 0.f, s1 = 0.f, s2 = 0.f, s3 = 0.f;
#pragma unroll
      for (int i = 0; i < 5; i++)
#pragma unroll
        for (int j = 0; j < 5; j++) {
          float v = G(i - 2, j - 2);
          s0 += e5[i][j] * v;
          s1 += e5[j][4 - i] * v;
          s2 += e5[4 - i][4 - j] * v;
          s3 += e5[4 - j][i] * v;
        }
      f[27] = s0 * 0.25f;
      f[28] = s1 * 0.25f;
      f[29] = s2 * 0.25f;
      f[30] = s3 * 0.25f;
    }
    {
      float gc = sgr[ly][lx];
      f[31] = gc - 0.25f * (sgr[ly - 1][lx] + sgr[ly][lx - 1] +
                            sgr[ly][lx + 1] + sgr[ly + 1][lx]);
    }
#undef G

    _Float16 h[32];
#pragma unroll
    for (int cc = 0; cc < 32; cc++) h[cc] = (_Float16)f[cc];
    floatx4* dst = (floatx4*)&F[(((size_t)b * H_ + (y0 + py)) * W_ + (x0 + px)) * 32];
    const floatx4* src = (const floatx4*)h;
#pragma unroll
    for (int k = 0; k < 4; k++) dst[k] = src[k];
  }
}

// ---------------------------------------------------------------------------
// Weight prep: OIHW fp32 -> [cin/8][9][64][8] fp16 (B-fragment friendly),
// plus folded BN scale/shift.
// ---------------------------------------------------------------------------
__global__ void wprep_kernel(const float* __restrict__ w,
                             const float* __restrict__ bias,
                             const float* __restrict__ g,
                             const float* __restrict__ be,
                             const float* __restrict__ m,
                             const float* __restrict__ v,
                             _Float16* __restrict__ wp,
                             float* __restrict__ sc, float* __restrict__ sh,
                             int cin) {
  int i = blockIdx.x * 256 + threadIdx.x;
  int total = cin * 9 * 64;
  if (i < total) {
    int j = i & 7;
    int co = (i >> 3) & 63;
    int rest = i >> 9;
    int t = rest % 9;
    int qc = rest / 9;
    int ci = qc * 8 + j;
    wp[i] = (_Float16)w[((size_t)co * cin + ci) * 9 + t];
  }
  if (i < 64) {
    float s = g[i] * rsqrtf(v[i] + 1e-5f);
    sc[i] = s;
    sh[i] = be[i] + (bias[i] - m[i]) * s;
  }
}

// ---------------------------------------------------------------------------
// Implicit-GEMM conv3x3 (SAME) + BN + ReLU via mfma_f32_16x16x32_f16.
// in: NHWC fp16 [B][H][W][CIN].  wp: [CIN/8][9][64][8] fp16.
// Block: 64(x) x 4(y) pixels, all 64 couts. 4 waves; wave w owns row y0+w.
// Wave tile: M=64 pixels x N=64 couts = 4x4 MFMA tiles (64 acc VGPRs).
// FINAL=false: out NHWC fp16 (LDS bounce). FINAL=true: out NCHW fp32.
// ---------------------------------------------------------------------------
template <int CIN, bool FINAL>
__global__ __launch_bounds__(256, 2) void conv_mfma(
    const _Float16* __restrict__ in, const _Float16* __restrict__ wp,
    const float* __restrict__ sc, const float* __restrict__ sh,
    void* __restrict__ outv) {
  // chunk-major layouts -> conflict-free b128 reads (bank math in journal)
  __shared__ _Float16 s_in[4][6][66][8];  // 25,344 B [ci8-chunk][row][col][8ci]
  __shared__ _Float16 s_w[4][9][64][8];   // 36,864 B [ci8-chunk][tap][co][8ci]

  const int tid = threadIdx.x;
  const int b = blockIdx.z;
  const int y0 = blockIdx.y * 4;
  const int x0 = blockIdx.x * 64;
  const int wid = tid >> 6;
  const int lane = tid & 63;
  const int quad = lane >> 4;
  const int ln = lane & 15;
  const int y = y0 + wid;

  floatx4 acc[4][4];
#pragma unroll
  for (int mt = 0; mt < 4; mt++)
#pragma unroll
    for (int nt = 0; nt < 4; nt++) acc[mt][nt] = (floatx4)0.f;

  for (int kc = 0; kc < CIN / 32; kc++) {
    __syncthreads();
    // stage input: 4 chunks x 6 rows x 66 cols, 16B each
    for (int i = tid; i < 4 * 6 * 66; i += 256) {
      int q = i & 3;
      int pos = i >> 2;
      int r = pos / 66, c = pos % 66;
      int gy = y0 + r - 1, gx = x0 + c - 1;
      floatx4 val = (floatx4)0.f;
      if (gy >= 0 && gy < H_ && gx >= 0 && gx < W_)
        val = *(const floatx4*)&in[(((size_t)b * H_ + gy) * W_ + gx) * CIN +
                                   kc * 32 + q * 8];
      *(floatx4*)&s_in[q][r][c][0] = val;
    }
    // stage weights: 4 chunks x 9 taps x 64 co, 16B each
    for (int i = tid; i < 4 * 9 * 64; i += 256) {
      int co = i & 63;
      int rest = i >> 6;
      int t = rest % 9;
      int q = rest / 9;
      *(floatx4*)&s_w[q][t][co][0] =
          *(const floatx4*)&wp[((((size_t)kc * 4 + q) * 9 + t) * 64 + co) * 8];
    }
    __syncthreads();

#pragma unroll
    for (int t = 0; t < 9; t++) {
      const int ty = t / 3, tx = t % 3;
      half8 a[4], bb[4];
#pragma unroll
      for (int mt = 0; mt < 4; mt++)
        a[mt] = *(const half8*)&s_in[quad][wid + ty][mt * 16 + ln + tx][0];
#pragma unroll
      for (int nt = 0; nt < 4; nt++)
        bb[nt] = *(const half8*)&s_w[quad][t][nt * 16 + ln][0];
#pragma unroll
      for (int mt = 0; mt < 4; mt++)
#pragma unroll
        for (int nt = 0; nt < 4; nt++)
          acc[mt][nt] = __builtin_amdgcn_mfma_f32_16x16x32_f16(
              a[mt], bb[nt], acc[mt][nt], 0, 0, 0);
    }
  }

  // ---- epilogue: BN + ReLU ----
  float vout[4][4][4];
#pragma unroll
  for (int nt = 0; nt < 4; nt++) {
    int co = nt * 16 + ln;
    float s = sc[co], t0 = sh[co];
#pragma unroll
    for (int mt = 0; mt < 4; mt++)
#pragma unroll
      for (int r = 0; r < 4; r++)
        vout[mt][nt][r] = fmaxf(acc[mt][nt][r] * s + t0, 0.f);
  }

  if (FINAL) {
    // NCHW fp32: lane writes 4 consecutive x (r-dim) per (mt,nt)
    float* out = (float*)outv;
#pragma unroll
    for (int mt = 0; mt < 4; mt++) {
#pragma unroll
      for (int nt = 0; nt < 4; nt++) {
        int co = nt * 16 + ln;
        int xb = x0 + mt * 16 + quad * 4;
        floatx4 vv;
#pragma unroll
        for (int r = 0; r < 4; r++) vv[r] = vout[mt][nt][r];
        *(floatx4*)&out[(((size_t)b * 64 + co) * H_ + y) * W_ + xb] = vv;
      }
    }
  } else {
    // NHWC fp16 via LDS bounce (reuse s_w: 4 waves x 8KB = 32KB <= 36,864B)
    __syncthreads();  // all MFMA reads of s_w done
    _Float16* s_out = &s_w[0][0][0][0] + wid * 4096;
#pragma unroll
    for (int mt = 0; mt < 4; mt++)
#pragma unroll
      for (int nt = 0; nt < 4; nt++)
#pragma unroll
        for (int r = 0; r < 4; r++) {
          int pix = mt * 16 + quad * 4 + r;
          int co = nt * 16 + ln;
          s_out[pix * 64 + co] = (_Float16)vout[mt][nt][r];
        }
    __syncthreads();
    _Float16* out = (_Float16*)outv;
    size_t base = (((size_t)b * H_ + y) * W_ + x0) * 64;
#pragma unroll
    for (int k = 0; k < 8; k++) {
      *(floatx4*)&out[base + (size_t)(k * 64 + lane) * 8] =
          *(const floatx4*)&s_out[(k * 64 + lane) * 8];
    }
  }
}

// ---------------------------------------------------------------------------
// Launch
// ---------------------------------------------------------------------------
extern "C" void kernel_launch(void* const* d_in, const int* in_sizes, int n_in,
                              void* d_out, int out_size, void* d_ws,
                              size_t ws_size, hipStream_t stream) {
  const float* x = (const float*)d_in[0];
#define LAYER_PTRS(i)                                                       \
  const float* w##i = (const float*)d_in[1 + ((i)-1) * 6 + 0];              \
  const float* b##i = (const float*)d_in[1 + ((i)-1) * 6 + 1];              \
  const float* g##i = (const float*)d_in[1 + ((i)-1) * 6 + 2];              \
  const float* be##i = (const float*)d_in[1 + ((i)-1) * 6 + 3];             \
  const float* m##i = (const float*)d_in[1 + ((i)-1) * 6 + 4];              \
  const float* v##i = (const float*)d_in[1 + ((i)-1) * 6 + 5];
  LAYER_PTRS(1)
  LAYER_PTRS(2)
  LAYER_PTRS(3)
  LAYER_PTRS(4)
#undef LAYER_PTRS

  char* ws = (char*)d_ws;
  _Float16* feat = (_Float16*)ws;                          // 67,108,864 B
  _Float16* actA = (_Float16*)(ws + 67108864);             // 134,217,728 B
  _Float16* actB = (_Float16*)(ws + 67108864 + 134217728); // 134,217,728 B
  char* wbase = ws + 67108864 + 2 * (size_t)134217728;
  _Float16* wp1 = (_Float16*)(wbase);
  _Float16* wp2 = (_Float16*)(wbase + 36864);
  _Float16* wp3 = (_Float16*)(wbase + 36864 + 73728);
  _Float16* wp4 = (_Float16*)(wbase + 36864 + 2 * 73728);
  float* scsh = (float*)(wbase + 36864 + 3 * 73728);
  float *sc1 = scsh, *sh1 = scsh + 64;
  float *sc2 = scsh + 128, *sh2 = scsh + 192;
  float *sc3 = scsh + 256, *sh3 = scsh + 320;
  float *sc4 = scsh + 384, *sh4 = scsh + 448;

  wprep_kernel<<<72, 256, 0, stream>>>(w1, b1, g1, be1, m1, v1, wp1, sc1, sh1, 32);
  wprep_kernel<<<144, 256, 0, stream>>>(w2, b2, g2, be2, m2, v2, wp2, sc2, sh2, 64);
  wprep_kernel<<<144, 256, 0, stream>>>(w3, b3, g3, be3, m3, v3, wp3, sc3, sh3, 64);
  wprep_kernel<<<144, 256, 0, stream>>>(w4, b4, g4, be4, m4, v4, wp4, sc4, sh4, 64);

  dim3 fgrid(W_ / 32, H_ / 32, B_);
  feat_kernel<<<fgrid, 256, 0, stream>>>(x, feat);

  dim3 cgrid(W_ / 64, H_ / 4, B_);
  conv_mfma<32, false><<<cgrid, 256, 0, stream>>>(feat, wp1, sc1, sh1, actA);
  conv_mfma<64, false><<<cgrid, 256, 0, stream>>>(actA, wp2, sc2, sh2, actB);
  conv_mfma<64, false><<<cgrid, 256, 0, stream>>>(actB, wp3, sc3, sh3, actA);
  conv_mfma<64, true><<<cgrid, 256, 0, stream>>>(actA, wp4, sc4, sh4, d_out);
}

// Round 3
// 728.652 us; speedup vs baseline: 5.3645x; 1.1295x over previous
//
#include <hip/hip_runtime.h>
#include <hip/hip_bf16.h>
#include <cstddef>

#define B_ 16
#define H_ 256
#define W_ 256
#define HW_ (H_ * W_)
#define P_ 258  // padded H/W for NHWC activation buffers

typedef _Float16 half8 __attribute__((ext_vector_type(8)));
typedef float floatx4 __attribute__((ext_vector_type(4)));

// async global->LDS 16B DMA (LDS dest must be wave-uniform base + lane*16;
// all call sites keep lds offset strictly linear in the per-lane loop index)
__device__ __forceinline__ void gload_lds16(void* lds, const void* g) {
  __builtin_amdgcn_global_load_lds(
      (const __attribute__((address_space(1))) unsigned int*)g,
      (__attribute__((address_space(3))) unsigned int*)lds, 16, 0, 0);
}

// ---------------------------------------------------------------------------
// Zero the 1-pixel border of a padded NHWC buffer [16][258][258][C] fp16.
// (ws is re-poisoned 0xAA before every launch, so this runs every call.)
// ---------------------------------------------------------------------------
template <int C>
__global__ __launch_bounds__(256) void zero_border(_Float16* __restrict__ buf) {
  int idx = blockIdx.x * 256 + threadIdx.x;
  int total = 16 * 1028 * (C / 8);
  if (idx >= total) return;
  int cg = idx % (C / 8);
  int rest = idx / (C / 8);
  int p = rest % 1028;
  int b = rest / 1028;
  int row, col;
  if (p < 258) { row = 0; col = p; }
  else if (p < 516) { row = 257; col = p - 258; }
  else if (p < 772) { row = p - 515; col = 0; }
  else { row = p - 771; col = 257; }
  *(floatx4*)&buf[(((size_t)b * P_ + row) * P_ + col) * C + cg * 8] = (floatx4)0.f;
}

// ---------------------------------------------------------------------------
// Feature extraction: x [B,3,H,W] fp32 -> F padded NHWC [B,258,258,32] fp16
// ---------------------------------------------------------------------------
__global__ __launch_bounds__(256) void feat_kernel(const float* __restrict__ x,
                                                   _Float16* __restrict__ F) {
  __shared__ float sg[36][37];
  __shared__ float sgr[36][37];

  const int b = blockIdx.z;
  const int y0 = blockIdx.y * 32;
  const int x0 = blockIdx.x * 32;
  const float* xb = x + (size_t)b * 3 * HW_;

  for (int i = threadIdx.x; i < 36 * 36; i += 256) {
    int iy = i / 36, ix = i % 36;
    int gy = y0 + iy - 2, gx = x0 + ix - 2;
    float gray = 0.f, green = 0.f;
    if (gy >= 0 && gy < H_ && gx >= 0 && gx < W_) {
      int idx = gy * W_ + gx;
      float r = fminf(fmaxf(xb[idx] * 0.229f + 0.485f, 0.f), 1.f);
      float g = fminf(fmaxf(xb[idx + HW_] * 0.224f + 0.456f, 0.f), 1.f);
      float bl = fminf(fmaxf(xb[idx + 2 * HW_] * 0.225f + 0.406f, 0.f), 1.f);
      gray = 0.299f * r + 0.587f * g + 0.114f * bl;
      green = g;
    }
    sg[iy][ix] = gray;
    sgr[iy][ix] = green;
  }
  __syncthreads();

  for (int p = threadIdx.x; p < 32 * 32; p += 256) {
    const int py = p >> 5, px = p & 31;
    const int ly = py + 2, lx = px + 2;
#define G(dy, dx) sg[ly + (dy)][lx + (dx)]
    float f[32];
    const float c = G(0, 0);

    {
      const float ga[5] = {1.f, 4.f, 6.f, 4.f, 1.f};
      float s = 0.f;
#pragma unroll
      for (int i = 0; i < 5; i++) {
        float rs = 0.f;
#pragma unroll
        for (int j = 0; j < 5; j++) rs += ga[j] * G(i - 2, j - 2);
        s += ga[i] * rs;
      }
      f[0] = c - s * (1.0f / 256.0f);
    }

    const int dy8[8] = {-1, -1, 0, 1, 1, 1, 0, -1};
    const int dx8[8] = {0, 1, 1, 1, 0, -1, -1, -1};

#pragma unroll
    for (int k = 0; k < 8; k++) f[1 + k] = G(dy8[k], dx8[k]) - c;
#pragma unroll
    for (int k = 0; k < 4; k++)
      f[9 + k] = 0.5f * (G(dy8[k], dx8[k]) + G(-dy8[k], -dx8[k])) - c;
#pragma unroll
    for (int k = 0; k < 8; k++)
      f[13 + k] = (-G(-dy8[k], -dx8[k]) + 3.f * c - 3.f * G(dy8[k], dx8[k]) +
                   G(2 * dy8[k], 2 * dx8[k])) * (1.f / 3.f);

    {
      const float sq3[3][3] = {{-1, 2, -1}, {2, -4, 2}, {-1, 2, -1}};
      float s = 0.f;
#pragma unroll
      for (int i = 0; i < 3; i++)
#pragma unroll
        for (int j = 0; j < 3; j++) s += sq3[i][j] * G(i - 1, j - 1);
      f[21] = s * 0.25f;
    }
    {
      const float sq5[5][5] = {{-1, 2, -2, 2, -1},
                               {2, -6, 8, -6, 2},
                               {-2, 8, -12, 8, -2},
                               {2, -6, 8, -6, 2},
                               {-1, 2, -2, 2, -1}};
      float s = 0.f;
#pragma unroll
      for (int i = 0; i < 5; i++)
#pragma unroll
        for (int j = 0; j < 5; j++) s += sq5[i][j] * G(i - 2, j - 2);
      f[22] = s * (1.0f / 12.0f);
    }
    {
      const float e3[3][3] = {{-1, 2, -1}, {2, -4, 2}, {0, 0, 0}};
      float s0 = 0.f, s1 = 0.f, s2 = 0.f, s3 = 0.f;
#pragma unroll
      for (int i = 0; i < 3; i++)
#pragma unroll
        for (int j = 0; j < 3; j++) {
          float v = G(i - 1, j - 1);
          s0 += e3[i][j] * v;
          s1 += e3[j][2 - i] * v;
          s2 += e3[2 - i][2 - j] * v;
          s3 += e3[2 - j][i] * v;
        }
      f[23] = s0 * 0.25f;
      f[24] = s1 * 0.25f;
      f[25] = s2 * 0.25f;
      f[26] = s3 * 0.25f;
    }
    {
      const float e5[5][5] = {{-1, 2, -2, 2, -1},
                              {2, -6, 8, -6, 2},
                              {-2, 8, -12, 8, -2},
                              {0, 0, 0, 0, 0},
                              {0, 0, 0, 0, 0}};
      float s0 = 0.f, s1 = 0.f, s2 = 0.f, s3 = 0.f;
#pragma unroll
      for (int i = 0; i < 5; i++)
#pragma unroll
        for (int j = 0; j < 5; j++) {
          float v = G(i - 2, j - 2);
          s0 += e5[i][j] * v;
          s1 += e5[j][4 - i] * v;
          s2 += e5[4 - i][4 - j] * v;
          s3 += e5[4 - j][i] * v;
        }
      f[27] = s0 * 0.25f;
      f[28] = s1 * 0.25f;
      f[29] = s2 * 0.25f;
      f[30] = s3 * 0.25f;
    }
    {
      float gc = sgr[ly][lx];
      f[31] = gc - 0.25f * (sgr[ly - 1][lx] + sgr[ly][lx - 1] +
                            sgr[ly][lx + 1] + sgr[ly + 1][lx]);
    }
#undef G

    _Float16 h[32];
#pragma unroll
    for (int cc = 0; cc < 32; cc++) h[cc] = (_Float16)f[cc];
    floatx4* dst =
        (floatx4*)&F[(((size_t)b * P_ + (y0 + py + 1)) * P_ + (x0 + px + 1)) * 32];
    const floatx4* src = (const floatx4*)h;
#pragma unroll
    for (int k = 0; k < 4; k++) dst[k] = src[k];
  }
}

// ---------------------------------------------------------------------------
// Weight prep: OIHW fp32 -> [cin/8][9][64][8] fp16 + folded BN scale/shift.
// Layout matches conv LDS layout exactly -> pure contiguous DMA staging.
// ---------------------------------------------------------------------------
__global__ void wprep_kernel(const float* __restrict__ w,
                             const float* __restrict__ bias,
                             const float* __restrict__ g,
                             const float* __restrict__ be,
                             const float* __restrict__ m,
                             const float* __restrict__ v,
                             _Float16* __restrict__ wp,
                             float* __restrict__ sc, float* __restrict__ sh,
                             int cin) {
  int i = blockIdx.x * 256 + threadIdx.x;
  int total = cin * 9 * 64;
  if (i < total) {
    int j = i & 7;
    int co = (i >> 3) & 63;
    int rest = i >> 9;
    int t = rest % 9;
    int qc = rest / 9;
    int ci = qc * 8 + j;
    wp[i] = (_Float16)w[((size_t)co * cin + ci) * 9 + t];
  }
  if (i < 64) {
    float s = g[i] * rsqrtf(v[i] + 1e-5f);
    sc[i] = s;
    sh[i] = be[i] + (bias[i] - m[i]) * s;
  }
}

// ---------------------------------------------------------------------------
// Implicit-GEMM conv3x3 + BN + ReLU via mfma_f32_16x16x32_f16.
// in: padded NHWC fp16 [B][258][258][CIN].  wp: [CIN/8][9][64][8] fp16.
// Block: 64(x) x 8(y) pixels, all 64 couts. 4 waves; wave w owns rows 2w,2w+1.
// Wave tile: M=128 x N=64 = 8x4 MFMA tiles -> per tap 12 b128 reads : 32 MFMA.
// Staging entirely via global_load_lds (no bounds checks thanks to padding).
// FINAL=false: out padded NHWC fp16 (LDS bounce). FINAL=true: out NCHW fp32.
// ---------------------------------------------------------------------------
template <int CIN, bool FINAL>
__global__ __launch_bounds__(256, 2) void conv_mfma(
    const _Float16* __restrict__ in, const _Float16* __restrict__ wp,
    const float* __restrict__ sc, const float* __restrict__ sh,
    void* __restrict__ outv) {
  // single LDS block: s_in [4][10][66][8] (42,240B) then s_w [4][9][64][8]
  __shared__ char smem[42240 + 36864];
  _Float16(*s_in)[10][66][8] = (_Float16(*)[10][66][8])smem;
  _Float16(*s_w)[9][64][8] = (_Float16(*)[9][64][8])(smem + 42240);

  const int tid = threadIdx.x;
  const int b = blockIdx.z;
  const int y0 = blockIdx.y * 8;
  const int x0 = blockIdx.x * 64;
  const int wid = tid >> 6;
  const int lane = tid & 63;
  const int quad = lane >> 4;
  const int ln = lane & 15;

  floatx4 acc[8][4];
#pragma unroll
  for (int mt = 0; mt < 8; mt++)
#pragma unroll
    for (int nt = 0; nt < 4; nt++) acc[mt][nt] = (floatx4)0.f;

  for (int kc = 0; kc < CIN / 32; kc++) {
    __syncthreads();
    // input stage: 2640 16B units, LDS offset linear in i (wave-uniform+lane*16)
    for (int i = tid; i < 2640; i += 256) {
      int q = i / 660, rem = i % 660;
      int row = rem / 66, col = rem % 66;
      gload_lds16(smem + i * 16,
                  &in[(((size_t)b * P_ + (y0 + row)) * P_ + (x0 + col)) * CIN +
                      kc * 32 + q * 8]);
    }
    // weight stage: 2304 16B units, global layout == LDS layout
    for (int i = tid; i < 2304; i += 256) {
      gload_lds16(smem + 42240 + i * 16, wp + ((size_t)kc * 2304 + i) * 8);
    }
    __syncthreads();

#pragma unroll
    for (int t = 0; t < 9; t++) {
      const int ty = t / 3, tx = t % 3;
      half8 a[8], bb[4];
#pragma unroll
      for (int nt = 0; nt < 4; nt++)
        bb[nt] = *(const half8*)&s_w[quad][t][nt * 16 + ln][0];
#pragma unroll
      for (int mt = 0; mt < 8; mt++)
        a[mt] = *(const half8*)
            &s_in[quad][2 * wid + ty + (mt >> 2)][(mt & 3) * 16 + ln + tx][0];
#pragma unroll
      for (int mt = 0; mt < 8; mt++)
#pragma unroll
        for (int nt = 0; nt < 4; nt++)
          acc[mt][nt] = __builtin_amdgcn_mfma_f32_16x16x32_f16(
              a[mt], bb[nt], acc[mt][nt], 0, 0, 0);
    }
  }

  if (FINAL) {
    // NCHW fp32 direct: in-lane 4 accs = 4 consecutive x -> dwordx4 stores
    float* out = (float*)outv;
#pragma unroll
    for (int nt = 0; nt < 4; nt++) {
      int co = nt * 16 + ln;
      float s = sc[co], t0 = sh[co];
#pragma unroll
      for (int mt = 0; mt < 8; mt++) {
        int y = y0 + 2 * wid + (mt >> 2);
        int xb = x0 + (mt & 3) * 16 + quad * 4;
        floatx4 vv;
#pragma unroll
        for (int r = 0; r < 4; r++) vv[r] = fmaxf(acc[mt][nt][r] * s + t0, 0.f);
        *(floatx4*)&out[(((size_t)b * 64 + co) * H_ + y) * W_ + xb] = vv;
      }
    }
  } else {
    // padded NHWC fp16 via per-wave 16KB LDS bounce (smem reused)
    __syncthreads();  // all MFMA LDS reads done before overwrite
    _Float16* s_out = (_Float16*)smem + wid * 8192;
#pragma unroll
    for (int nt = 0; nt < 4; nt++) {
      int co = nt * 16 + ln;
      float s = sc[co], t0 = sh[co];
#pragma unroll
      for (int mt = 0; mt < 8; mt++) {
        int base = ((mt >> 2) * 64 + (mt & 3) * 16 + quad * 4) * 64 + co;
#pragma unroll
        for (int r = 0; r < 4; r++)
          s_out[base + r * 64] = (_Float16)fmaxf(acc[mt][nt][r] * s + t0, 0.f);
      }
    }
    _Float16* out = (_Float16*)outv;
#pragma unroll
    for (int k = 0; k < 16; k++) {
      int u = k * 64 + lane;
      int cog = u & 7, px = (u >> 3) & 63, rw = u >> 9;
      int gy = y0 + 2 * wid + rw + 1, gx = x0 + px + 1;
      *(floatx4*)&out[(((size_t)b * P_ + gy) * P_ + gx) * 64 + cog * 8] =
          *(const floatx4*)&s_out[u * 8];
    }
  }
}

// ---------------------------------------------------------------------------
// Launch
// ---------------------------------------------------------------------------
extern "C" void kernel_launch(void* const* d_in, const int* in_sizes, int n_in,
                              void* d_out, int out_size, void* d_ws,
                              size_t ws_size, hipStream_t stream) {
  const float* x = (const float*)d_in[0];
#define LAYER_PTRS(i)                                                       \
  const float* w##i = (const float*)d_in[1 + ((i)-1) * 6 + 0];              \
  const float* b##i = (const float*)d_in[1 + ((i)-1) * 6 + 1];              \
  const float* g##i = (const float*)d_in[1 + ((i)-1) * 6 + 2];              \
  const float* be##i = (const float*)d_in[1 + ((i)-1) * 6 + 3];             \
  const float* m##i = (const float*)d_in[1 + ((i)-1) * 6 + 4];              \
  const float* v##i = (const float*)d_in[1 + ((i)-1) * 6 + 5];
  LAYER_PTRS(1)
  LAYER_PTRS(2)
  LAYER_PTRS(3)
  LAYER_PTRS(4)
#undef LAYER_PTRS

  char* ws = (char*)d_ws;
  const size_t featB = (size_t)16 * P_ * P_ * 32 * 2;  // 68,161,536
  const size_t actB64 = (size_t)16 * P_ * P_ * 64 * 2; // 136,323,072
  _Float16* feat = (_Float16*)ws;
  _Float16* actA = (_Float16*)(ws + featB);
  _Float16* actB = (_Float16*)(ws + featB + actB64);
  char* wbase = ws + featB + 2 * actB64;
  _Float16* wp1 = (_Float16*)(wbase);
  _Float16* wp2 = (_Float16*)(wbase + 36864);
  _Float16* wp3 = (_Float16*)(wbase + 36864 + 73728);
  _Float16* wp4 = (_Float16*)(wbase + 36864 + 2 * 73728);
  float* scsh = (float*)(wbase + 36864 + 3 * 73728);
  float *sc1 = scsh, *sh1 = scsh + 64;
  float *sc2 = scsh + 128, *sh2 = scsh + 192;
  float *sc3 = scsh + 256, *sh3 = scsh + 320;
  float *sc4 = scsh + 384, *sh4 = scsh + 448;

  wprep_kernel<<<72, 256, 0, stream>>>(w1, b1, g1, be1, m1, v1, wp1, sc1, sh1, 32);
  wprep_kernel<<<144, 256, 0, stream>>>(w2, b2, g2, be2, m2, v2, wp2, sc2, sh2, 64);
  wprep_kernel<<<144, 256, 0, stream>>>(w3, b3, g3, be3, m3, v3, wp3, sc3, sh3, 64);
  wprep_kernel<<<144, 256, 0, stream>>>(w4, b4, g4, be4, m4, v4, wp4, sc4, sh4, 64);

  zero_border<32><<<257, 256, 0, stream>>>(feat);
  zero_border<64><<<514, 256, 0, stream>>>(actA);
  zero_border<64><<<514, 256, 0, stream>>>(actB);

  dim3 fgrid(W_ / 32, H_ / 32, B_);
  feat_kernel<<<fgrid, 256, 0, stream>>>(x, feat);

  dim3 cgrid(W_ / 64, H_ / 8, B_);
  conv_mfma<32, false><<<cgrid, 256, 0, stream>>>(feat, wp1, sc1, sh1, actA);
  conv_mfma<64, false><<<cgrid, 256, 0, stream>>>(actA, wp2, sc2, sh2, actB);
  conv_mfma<64, false><<<cgrid, 256, 0, stream>>>(actB, wp3, sc3, sh3, actA);
  conv_mfma<64, true><<<cgrid, 256, 0, stream>>>(actA, wp4, sc4, sh4, d_out);
}